// Round 1
// baseline (7987.379 us; speedup 1.0000x reference)
//
#include <hip/hip_runtime.h>
#include <hip/hip_bf16.h>

#define HW 65536
constexpr int IMG_H = 256, IMG_W = 256, NB = 8;

__device__ __forceinline__ float bf2f(unsigned short u) {
    return __uint_as_float(((unsigned)u) << 16);
}
__device__ __forceinline__ unsigned short f2bf(float f) {
    __hip_bfloat16 h = __float2bfloat16(f);
    return *reinterpret_cast<unsigned short*>(&h);
}

// ---------------- direct 3x3 SAME conv ----------------
// grid: x = 64 spatial tiles (8x8 grid of 32x32), y = COUT/16, z = batch
// block: 256 threads; each thread: 4 pixels x 16 out-channels in registers.
template<int CIN, int COUT, int ICB, bool IN_F32, bool OUT_F32>
__global__ __launch_bounds__(256) void conv3x3_kernel(
    const void* __restrict__ in_, const float* __restrict__ wt,
    const float* __restrict__ bias, void* __restrict__ out_)
{
    constexpr int OCB = 16;
    const int tile = blockIdx.x;
    const int ty0 = (tile >> 3) << 5;
    const int tx0 = (tile & 7) << 5;
    const int oc0 = blockIdx.y * OCB;
    const int b = blockIdx.z;

    __shared__ alignas(16) float s_in[ICB][34][36];
    __shared__ alignas(16) float s_w[ICB][9][OCB];

    const int tid = threadIdx.x;
    const int lx = tid & 31;   // 0..31  column
    const int ly = tid >> 5;   // 0..7   row base (pixels ly, ly+8, ly+16, ly+24)

    float acc[4][OCB];
    #pragma unroll
    for (int j = 0; j < 4; ++j)
        #pragma unroll
        for (int oc = 0; oc < OCB; ++oc) acc[j][oc] = 0.f;

    for (int ic0 = 0; ic0 < CIN; ic0 += ICB) {
        __syncthreads();
        // stage input tile (34x34 with halo, zero-padded at borders)
        for (int idx = tid; idx < ICB * 34 * 34; idx += 256) {
            int ic  = idx / (34 * 34);
            int rem = idx - ic * (34 * 34);
            int r   = rem / 34;
            int cc  = rem - r * 34;
            int gy = ty0 - 1 + r, gx = tx0 - 1 + cc;
            float v = 0.f;
            if ((unsigned)gy < (unsigned)IMG_H && (unsigned)gx < (unsigned)IMG_W) {
                size_t off = ((size_t)(b * CIN + ic0 + ic)) * HW + (size_t)gy * IMG_W + gx;
                v = IN_F32 ? ((const float*)in_)[off]
                           : bf2f(((const unsigned short*)in_)[off]);
            }
            s_in[ic][r][cc] = v;
        }
        // stage weights: w[oc][ic][ky][kx] -> s_w[ic][tap][oc]
        for (int idx = tid; idx < ICB * 9 * OCB; idx += 256) {
            int oc  = idx & (OCB - 1);
            int t2  = idx >> 4;
            int tap = t2 % 9;
            int ic  = t2 / 9;
            s_w[ic][tap][oc] = wt[((size_t)(oc0 + oc) * CIN + ic0 + ic) * 9 + tap];
        }
        __syncthreads();

        for (int ic = 0; ic < ICB; ++ic) {
            #pragma unroll
            for (int tap = 0; tap < 9; ++tap) {
                const int dy = tap / 3, dx = tap % 3;
                float wr[OCB];
                #pragma unroll
                for (int q = 0; q < OCB / 4; ++q)
                    *(float4*)&wr[q * 4] = *(const float4*)&s_w[ic][tap][q * 4];
                #pragma unroll
                for (int j = 0; j < 4; ++j) {
                    float iv = s_in[ic][ly + 8 * j + dy][lx + dx];
                    #pragma unroll
                    for (int oc = 0; oc < OCB; ++oc) acc[j][oc] += iv * wr[oc];
                }
            }
        }
    }

    #pragma unroll
    for (int oc = 0; oc < OCB; ++oc) {
        float bv = bias[oc0 + oc];
        size_t cbase = ((size_t)(b * COUT + oc0 + oc)) * HW;
        #pragma unroll
        for (int j = 0; j < 4; ++j) {
            int oy = ty0 + ly + 8 * j, ox = tx0 + lx;
            float v = acc[j][oc] + bv;
            size_t off = cbase + (size_t)oy * IMG_W + ox;
            if (OUT_F32) ((float*)out_)[off] = v;
            else ((__hip_bfloat16*)out_)[off] = __float2bfloat16(v);
        }
    }
}

// ---------------- BatchNorm stats: per-channel partial sums ----------------
// grid: (C, B); deterministic block-tree reduction, partial[c*B + b] = (sum, sumsq)
template<bool F32>
__global__ __launch_bounds__(256) void bn_stats_kernel(const void* __restrict__ raw,
                                                       float2* __restrict__ partial, int C)
{
    int c = blockIdx.x, b = blockIdx.y;
    size_t base = ((size_t)(b * C + c)) * HW;
    float s = 0.f, ss = 0.f;
    if (F32) {
        const float4* p = (const float4*)((const float*)raw + base);
        for (int i = threadIdx.x; i < HW / 4; i += 256) {
            float4 v = p[i];
            s  += v.x + v.y + v.z + v.w;
            ss += v.x * v.x + v.y * v.y + v.z * v.z + v.w * v.w;
        }
    } else {
        const ushort4* p = (const ushort4*)((const unsigned short*)raw + base);
        for (int i = threadIdx.x; i < HW / 4; i += 256) {
            ushort4 u = p[i];
            float a = bf2f(u.x), b2 = bf2f(u.y), c2 = bf2f(u.z), d2 = bf2f(u.w);
            s  += a + b2 + c2 + d2;
            ss += a * a + b2 * b2 + c2 * c2 + d2 * d2;
        }
    }
    __shared__ float rs[256], rss[256];
    rs[threadIdx.x] = s; rss[threadIdx.x] = ss;
    __syncthreads();
    for (int off = 128; off; off >>= 1) {
        if (threadIdx.x < off) {
            rs[threadIdx.x]  += rs[threadIdx.x + off];
            rss[threadIdx.x] += rss[threadIdx.x + off];
        }
        __syncthreads();
    }
    if (threadIdx.x == 0)
        partial[(size_t)c * gridDim.y + b] = make_float2(rs[0], rss[0]);
}

// ---------------- finalize: mean/var -> scale/shift ----------------
__global__ void bn_finalize_kernel(const float2* __restrict__ partial,
                                   const float* __restrict__ gamma,
                                   const float* __restrict__ beta,
                                   float2* __restrict__ coef, int C, int nchunk)
{
    int c = threadIdx.x;
    if (c >= C) return;
    float s = 0.f, ss = 0.f;
    for (int i = 0; i < nchunk; ++i) {
        float2 p = partial[(size_t)c * nchunk + i];
        s += p.x; ss += p.y;
    }
    const float N = 524288.f;  // B*H*W
    float m = s / N;
    float v = ss / N - m * m;
    float rsq = rsqrtf(v + 1e-5f);
    float a = gamma[c] * rsq;
    coef[c] = make_float2(a, beta[c] - m * a);
}

// ---------------- in-place normalize + LeakyReLU (4 elems/thread) ----------------
template<bool F32>
__global__ __launch_bounds__(256) void bn_apply_kernel(void* __restrict__ data,
                                                       const float2* __restrict__ coef, int C)
{
    size_t q = (size_t)blockIdx.x * 256 + threadIdx.x;   // quad index (grid sized exactly)
    int c = (int)((q >> 14) & (size_t)(C - 1));          // (q*4)/65536 % C, C is pow2
    float2 ab = coef[c];
    if (F32) {
        float4* p = (float4*)data;
        float4 v = p[q];
        float x0 = ab.x * v.x + ab.y; v.x = x0 > 0.f ? x0 : 0.01f * x0;
        float x1 = ab.x * v.y + ab.y; v.y = x1 > 0.f ? x1 : 0.01f * x1;
        float x2 = ab.x * v.z + ab.y; v.z = x2 > 0.f ? x2 : 0.01f * x2;
        float x3 = ab.x * v.w + ab.y; v.w = x3 > 0.f ? x3 : 0.01f * x3;
        p[q] = v;
    } else {
        ushort4* p = (ushort4*)data;
        ushort4 u = p[q];
        float x0 = ab.x * bf2f(u.x) + ab.y; x0 = x0 > 0.f ? x0 : 0.01f * x0;
        float x1 = ab.x * bf2f(u.y) + ab.y; x1 = x1 > 0.f ? x1 : 0.01f * x1;
        float x2 = ab.x * bf2f(u.z) + ab.y; x2 = x2 > 0.f ? x2 : 0.01f * x2;
        float x3 = ab.x * bf2f(u.w) + ab.y; x3 = x3 > 0.f ? x3 : 0.01f * x3;
        u.x = f2bf(x0); u.y = f2bf(x1); u.z = f2bf(x2); u.w = f2bf(x3);
        p[q] = u;
    }
}

// ---------------- 9x9 patch extraction around anchors ----------------
__global__ void patches_kernel(const float* __restrict__ x, const int* __restrict__ hw,
                               float* __restrict__ out)
{
    int bs = blockIdx.x;           // b*32 + s
    int b = bs >> 5;
    int h = hw[bs * 2], w = hw[bs * 2 + 1];
    int t = threadIdx.x;
    if (t < 243) {
        int c = t / 81, r = (t / 9) % 9, cc = t % 9;
        out[(size_t)bs * 243 + t] =
            x[((size_t)(b * 3 + c)) * HW + (size_t)(h - 4 + r) * IMG_W + (w - 4 + cc)];
    }
}

// ---------------- pointwise latent gather: out[b][s][l] = z[b][l][h][w] ----------------
__global__ void gather_kernel(const float* __restrict__ z, const int* __restrict__ hw,
                              float* __restrict__ out)
{
    int bs = blockIdx.x;
    int b = bs >> 5;
    int h = hw[bs * 2], w = hw[bs * 2 + 1];
    int l = threadIdx.x;           // 256 = L
    out[(size_t)bs * 256 + l] = z[((size_t)(b * 256 + l)) * HW + (size_t)h * IMG_W + w];
}

// ---------------- recon: out[b][n] = sum_k za[b][k]*rw[n][k] + rb[n] ----------------
// block = 4 waves; each wave owns 4 consecutive n, k-loop coalesced float4.
__global__ __launch_bounds__(256) void recon_kernel(const float* __restrict__ za,
                                                    const float* __restrict__ rw,
                                                    const float* __restrict__ rb,
                                                    float* __restrict__ out)
{
    int wave = threadIdx.x >> 6, lane = threadIdx.x & 63;
    int n0 = blockIdx.x * 16 + wave * 4;
    float acc[4][8];
    #pragma unroll
    for (int j = 0; j < 4; ++j)
        #pragma unroll
        for (int bb = 0; bb < 8; ++bb) acc[j][bb] = 0.f;

    for (int i = 0; i < 32; ++i) {              // 8192 / (64 lanes * 4)
        int k = i * 256 + lane * 4;
        float4 wv[4];
        #pragma unroll
        for (int j = 0; j < 4; ++j)
            wv[j] = *(const float4*)&rw[(size_t)(n0 + j) * 8192 + k];
        #pragma unroll
        for (int bb = 0; bb < 8; ++bb) {
            float4 zv = *(const float4*)&za[(size_t)bb * 8192 + k];
            #pragma unroll
            for (int j = 0; j < 4; ++j)
                acc[j][bb] += zv.x * wv[j].x + zv.y * wv[j].y + zv.z * wv[j].z + zv.w * wv[j].w;
        }
    }
    #pragma unroll
    for (int j = 0; j < 4; ++j)
        #pragma unroll
        for (int bb = 0; bb < 8; ++bb) {
            float v = acc[j][bb];
            #pragma unroll
            for (int off = 32; off; off >>= 1) v += __shfl_down(v, off);
            if (lane == 0) out[(size_t)bb * 7776 + n0 + j] = v + rb[n0 + j];
        }
}

extern "C" void kernel_launch(void* const* d_in, const int* in_sizes, int n_in,
                              void* d_out, int out_size, void* d_ws, size_t ws_size,
                              hipStream_t stream) {
    (void)in_sizes; (void)n_in; (void)out_size; (void)ws_size;

    const float* x        = (const float*)d_in[0];
    const int* anchors    = (const int*)d_in[1];
    const int* positives  = (const int*)d_in[2];
    const float* w1 = (const float*)d_in[3];  const float* b1 = (const float*)d_in[4];
    const float* g1 = (const float*)d_in[5];  const float* be1 = (const float*)d_in[6];
    const float* w2 = (const float*)d_in[7];  const float* b2 = (const float*)d_in[8];
    const float* g2 = (const float*)d_in[9];  const float* be2 = (const float*)d_in[10];
    const float* w3 = (const float*)d_in[11]; const float* b3 = (const float*)d_in[12];
    const float* g3 = (const float*)d_in[13]; const float* be3 = (const float*)d_in[14];
    const float* w4 = (const float*)d_in[15]; const float* b4 = (const float*)d_in[16];
    const float* g4 = (const float*)d_in[17]; const float* be4 = (const float*)d_in[18];
    const float* rw = (const float*)d_in[19]; const float* rb = (const float*)d_in[20];

    float* z  = (float*)d_out;                 // [8][256][256][256]
    float* xa = z + 134217728;                 // x_anchors_flat [8][7776]
    float* xr = xa + 62208;                    // x_recon        [8][7776]
    float* za = xr + 62208;                    // z_anchors      [8][32][256]
    float* zp = za + 65536;                    // z_positives    [8][32][256]

    char* ws = (char*)d_ws;
    __hip_bfloat16* bufP = (__hip_bfloat16*)ws;                      // 134,217,728 B (act1/act3)
    __hip_bfloat16* bufQ = (__hip_bfloat16*)(ws + 134217728ull);     //  67,108,864 B (act2)
    float2* partial = (float2*)(ws + 201326592ull);                  // 16 KB
    float2* coef    = (float2*)(ws + 201326592ull + 16384ull);       // 2 KB

    // stage 1: x (f32) -> bufP (bf16 raw), BN+LeakyReLU in place
    conv3x3_kernel<3, 32, 3, true, false><<<dim3(64, 2, 8), 256, 0, stream>>>(x, w1, b1, bufP);
    bn_stats_kernel<false><<<dim3(32, 8), 256, 0, stream>>>(bufP, partial, 32);
    bn_finalize_kernel<<<1, 256, 0, stream>>>(partial, g1, be1, coef, 32, 8);
    bn_apply_kernel<false><<<16384, 256, 0, stream>>>(bufP, coef, 32);

    // stage 2: bufP -> bufQ
    conv3x3_kernel<32, 64, 8, false, false><<<dim3(64, 4, 8), 256, 0, stream>>>(bufP, w2, b2, bufQ);
    bn_stats_kernel<false><<<dim3(64, 8), 256, 0, stream>>>(bufQ, partial, 64);
    bn_finalize_kernel<<<1, 256, 0, stream>>>(partial, g2, be2, coef, 64, 8);
    bn_apply_kernel<false><<<32768, 256, 0, stream>>>(bufQ, coef, 64);

    // stage 3: bufQ -> bufP
    conv3x3_kernel<64, 128, 8, false, false><<<dim3(64, 8, 8), 256, 0, stream>>>(bufQ, w3, b3, bufP);
    bn_stats_kernel<false><<<dim3(128, 8), 256, 0, stream>>>(bufP, partial, 128);
    bn_finalize_kernel<<<1, 256, 0, stream>>>(partial, g3, be3, coef, 128, 8);
    bn_apply_kernel<false><<<65536, 256, 0, stream>>>(bufP, coef, 128);

    // stage 4: bufP -> z (f32 raw in d_out), BN+LeakyReLU in place
    conv3x3_kernel<128, 256, 8, false, true><<<dim3(64, 16, 8), 256, 0, stream>>>(bufP, w4, b4, z);
    bn_stats_kernel<true><<<dim3(256, 8), 256, 0, stream>>>(z, partial, 256);
    bn_finalize_kernel<<<1, 256, 0, stream>>>(partial, g4, be4, coef, 256, 8);
    bn_apply_kernel<true><<<131072, 256, 0, stream>>>(z, coef, 256);

    // aux outputs
    patches_kernel<<<256, 256, 0, stream>>>(x, anchors, xa);
    gather_kernel<<<256, 256, 0, stream>>>(z, anchors, za);
    gather_kernel<<<256, 256, 0, stream>>>(z, positives, zp);
    recon_kernel<<<486, 256, 0, stream>>>(za, rw, rb, xr);
}

// Round 2
// 1399.487 us; speedup vs baseline: 5.7074x; 5.7074x over previous
//
#include <hip/hip_runtime.h>
#include <hip/hip_bf16.h>

#define HW 65536
constexpr int IMG_H = 256, IMG_W = 256;

typedef __attribute__((ext_vector_type(8))) short short8;
typedef __attribute__((ext_vector_type(4))) float f32x4;

__device__ __forceinline__ float bf2f(unsigned short u) {
    return __uint_as_float(((unsigned)u) << 16);
}
__device__ __forceinline__ unsigned short f2bf(float f) {
    __hip_bfloat16 h = __float2bfloat16(f);
    return *reinterpret_cast<unsigned short*>(&h);
}

// ================= stage 1: direct 3x3 conv, NCHW f32 in -> NHWC bf16 raw out =================
// grid: (64 tiles of 32x32, COUT/16, batch)
__global__ __launch_bounds__(256) void conv1_direct(
    const float* __restrict__ x, const float* __restrict__ wt,
    const float* __restrict__ bias, unsigned short* __restrict__ outraw)
{
    constexpr int CIN = 3, COUT = 32, OCB = 16;
    const int tile = blockIdx.x;
    const int ty0 = (tile >> 3) << 5;
    const int tx0 = (tile & 7) << 5;
    const int oc0 = blockIdx.y * OCB;
    const int b = blockIdx.z;

    __shared__ alignas(16) float s_in[CIN][34][36];
    __shared__ alignas(16) float s_w[CIN][9][OCB];

    const int tid = threadIdx.x;
    const int lx = tid & 31;
    const int ly = tid >> 5;

    float acc[4][OCB];
    #pragma unroll
    for (int j = 0; j < 4; ++j)
        #pragma unroll
        for (int oc = 0; oc < OCB; ++oc) acc[j][oc] = 0.f;

    for (int idx = tid; idx < CIN * 34 * 34; idx += 256) {
        int ic  = idx / (34 * 34);
        int rem = idx - ic * (34 * 34);
        int r   = rem / 34;
        int cc  = rem - r * 34;
        int gy = ty0 - 1 + r, gx = tx0 - 1 + cc;
        float v = 0.f;
        if ((unsigned)gy < 256u && (unsigned)gx < 256u)
            v = x[((size_t)(b * CIN + ic)) * HW + (size_t)gy * IMG_W + gx];
        s_in[ic][r][cc] = v;
    }
    for (int idx = tid; idx < CIN * 9 * OCB; idx += 256) {
        int oc  = idx & (OCB - 1);
        int t2  = idx >> 4;
        int tap = t2 % 9;
        int ic  = t2 / 9;
        s_w[ic][tap][oc] = wt[((size_t)(oc0 + oc) * CIN + ic) * 9 + tap];
    }
    __syncthreads();

    for (int ic = 0; ic < CIN; ++ic) {
        #pragma unroll
        for (int tap = 0; tap < 9; ++tap) {
            const int dy = tap / 3, dx = tap % 3;
            float wr[OCB];
            #pragma unroll
            for (int q = 0; q < OCB / 4; ++q)
                *(float4*)&wr[q * 4] = *(const float4*)&s_w[ic][tap][q * 4];
            #pragma unroll
            for (int j = 0; j < 4; ++j) {
                float iv = s_in[ic][ly + 8 * j + dy][lx + dx];
                #pragma unroll
                for (int oc = 0; oc < OCB; ++oc) acc[j][oc] += iv * wr[oc];
            }
        }
    }

    #pragma unroll
    for (int j = 0; j < 4; ++j) {
        const size_t p = ((size_t)b << 16) + (size_t)((ty0 + ly + 8 * j) << 8) + tx0 + lx;
        short8 v0, v1;
        #pragma unroll
        for (int k = 0; k < 8; ++k) {
            v0[k] = (short)f2bf(acc[j][k] + bias[oc0 + k]);
            v1[k] = (short)f2bf(acc[j][8 + k] + bias[oc0 + 8 + k]);
        }
        *(short8*)&outraw[p * COUT + oc0]     = v0;
        *(short8*)&outraw[p * COUT + oc0 + 8] = v1;
    }
}

// ================= weight repack: [oc][ic][3][3] f32 -> [oc][tap*CIN+ic] bf16 =================
__global__ void repack_w(const float* __restrict__ w, unsigned short* __restrict__ wp,
                         int COUT, int CIN)
{
    int i = blockIdx.x * 256 + threadIdx.x;
    int K9 = 9 * CIN;
    if (i >= COUT * K9) return;
    int oc = i / K9, k = i - oc * K9;
    int tap = k / CIN, ic = k - tap * CIN;
    wp[i] = f2bf(w[((size_t)(oc * CIN + ic)) * 9 + tap]);
}

// ================= MFMA implicit-GEMM 3x3 conv =================
// in: raw NHWC bf16 of prev stage (pre-BN); staging fuses prev BN coef + leaky.
// out: NHWC bf16 raw (OUT_NCHW=false) or NCHW f32 raw into d_out z (OUT_NCHW=true).
// block tile: 128 px (8 rows x 16 cols) x 64 oc; 4 waves, wave = 64 px x 32 oc.
template<int CIN, int COUT, bool OUT_NCHW>
__global__ __launch_bounds__(256, 2) void conv_mfma(
    const unsigned short* __restrict__ in, const float2* __restrict__ coef,
    const unsigned short* __restrict__ wp, const float* __restrict__ bias,
    void* __restrict__ out)
{
    constexpr int CINP = CIN + 8;
    constexpr int K9 = 9 * CIN;
    constexpr int NOC = COUT / 64;
    constexpr int SIN_SH = 10 * 18 * CINP;          // shorts
    static_assert(!OUT_NCHW || 2 * SIN_SH >= 64 * 132 * 4, "s_out must fit");
    __shared__ alignas(16) short s_in[SIN_SH];
    __shared__ float2 s_coef[CIN];

    const int bx = blockIdx.x;
    const int tile = bx / NOC;
    const int oc0 = (bx - tile * NOC) * 64;
    const int b = blockIdx.z;
    const int ty0 = (tile >> 4) << 3;               // 32 row-tiles of 8
    const int tx0 = (tile & 15) << 4;               // 16 col-tiles of 16

    const int tid = threadIdx.x;
    if (tid < CIN) s_coef[tid] = coef[tid];
    __syncthreads();

    // ---- stage input tile (10x18 halo, channels-last) with fused BN+leaky ----
    constexpr int NOCT = CIN / 8;
    const size_t bbase = (size_t)b << 16;
    for (int idx = tid; idx < 10 * 18 * NOCT; idx += 256) {
        int ic8 = idx % NOCT;
        int rc  = idx / NOCT;
        int c = rc % 18, r = rc / 18;
        int gy = ty0 - 1 + r, gx = tx0 - 1 + c;
        short8 v = (short8)0;
        if ((unsigned)gy < 256u && (unsigned)gx < 256u) {
            short8 rawv = *(const short8*)&in[(bbase + (size_t)(gy << 8) + gx) * CIN + ic8 * 8];
            #pragma unroll
            for (int j = 0; j < 8; ++j) {
                float2 ab = s_coef[ic8 * 8 + j];
                float xv = ab.x * bf2f((unsigned short)rawv[j]) + ab.y;
                xv = xv > 0.f ? xv : 0.01f * xv;
                v[j] = (short)f2bf(xv);
            }
        }
        *(short8*)&s_in[(r * 18 + c) * CINP + ic8 * 8] = v;
    }
    __syncthreads();

    // ---- MFMA k-loop (barrier-free; A from LDS, B from global/L2) ----
    const int lane = tid & 63;
    const int wv = tid >> 6;
    const int wm = wv >> 1, wn = wv & 1;
    const int ln = lane & 15;
    const int ks = (lane >> 4) * 8;

    f32x4 acc[4][2] = {};

    const size_t wrow0 = (size_t)(oc0 + wn * 32 + ln) * K9;
    const size_t wrow1 = (size_t)(oc0 + wn * 32 + 16 + ln) * K9;

    for (int tap = 0; tap < 9; ++tap) {
        const int dy = tap / 3, dx = tap - dy * 3;
        const int abase = ((wm * 4 + dy) * 18 + ln + dx) * CINP + ks;
        const int wbase = tap * CIN + ks;
        #pragma unroll
        for (int icb = 0; icb < CIN / 32; ++icb) {
            short8 b0 = *(const short8*)&wp[wrow0 + wbase + icb * 32];
            short8 b1 = *(const short8*)&wp[wrow1 + wbase + icb * 32];
            #pragma unroll
            for (int f = 0; f < 4; ++f) {
                short8 av = *(const short8*)&s_in[abase + f * (18 * CINP) + icb * 32];
                acc[f][0] = __builtin_amdgcn_mfma_f32_16x16x32_bf16(av, b0, acc[f][0], 0, 0, 0);
                acc[f][1] = __builtin_amdgcn_mfma_f32_16x16x32_bf16(av, b1, acc[f][1], 0, 0, 0);
            }
        }
    }

    // ---- epilogue ----
    if (!OUT_NCHW) {
        unsigned short* o = (unsigned short*)out;
        #pragma unroll
        for (int g = 0; g < 2; ++g) {
            const int oc = oc0 + wn * 32 + g * 16 + ln;
            const float bv = bias[oc];
            #pragma unroll
            for (int f = 0; f < 4; ++f) {
                const int rr = wm * 4 + f;
                #pragma unroll
                for (int reg = 0; reg < 4; ++reg) {
                    const int px = (lane >> 4) * 4 + reg;
                    const size_t p = bbase + (size_t)((ty0 + rr) << 8) + tx0 + px;
                    o[p * COUT + oc] = f2bf(acc[f][g][reg] + bv);
                }
            }
        }
    } else {
        __syncthreads();                       // done reading s_in
        float* s_out = (float*)s_in;           // [64][132] f32
        #pragma unroll
        for (int g = 0; g < 2; ++g) {
            const int ocl = wn * 32 + g * 16 + ln;
            const float bv = bias[oc0 + ocl];
            #pragma unroll
            for (int f = 0; f < 4; ++f) {
                const int rr = wm * 4 + f;
                #pragma unroll
                for (int reg = 0; reg < 4; ++reg) {
                    const int px = rr * 16 + (lane >> 4) * 4 + reg;
                    s_out[ocl * 132 + px] = acc[f][g][reg] + bv;
                }
            }
        }
        __syncthreads();
        float* zo = (float*)out;
        const int x4 = tid & 3, rr = (tid >> 2) & 7, oc8 = tid >> 5;
        #pragma unroll
        for (int pass = 0; pass < 8; ++pass) {
            const int ocl = pass * 8 + oc8;
            f32x4 v = *(const f32x4*)&s_out[ocl * 132 + rr * 16 + x4 * 4];
            *(f32x4*)&zo[(((size_t)b * 256 + oc0 + ocl) << 16)
                         + (size_t)((ty0 + rr) << 8) + tx0 + x4 * 4] = v;
        }
    }
}

// ================= BN stats over NHWC bf16 raw: partial[ch*256 + blk] =================
template<int C>
__global__ __launch_bounds__(256) void bn_stats_nhwc(const unsigned short* __restrict__ raw,
                                                     float2* __restrict__ partial)
{
    constexpr int CPT = C / 8;        // threads covering one pixel
    constexpr int PPI = 256 / CPT;    // pixels per iteration
    const int t = threadIdx.x;
    const int co = t % CPT, pg = t / CPT;
    const int p0 = blockIdx.x * 2048;  // 524288 / 256 blocks
    float s[8], ss[8];
    #pragma unroll
    for (int j = 0; j < 8; ++j) { s[j] = 0.f; ss[j] = 0.f; }
    for (int p = p0 + pg; p < p0 + 2048; p += PPI) {
        short8 v = *(const short8*)&raw[(size_t)p * C + co * 8];
        #pragma unroll
        for (int j = 0; j < 8; ++j) {
            float xv = bf2f((unsigned short)v[j]);
            s[j] += xv; ss[j] += xv * xv;
        }
    }
    __shared__ float rs[256][8], rss[256][8];
    #pragma unroll
    for (int j = 0; j < 8; ++j) { rs[t][j] = s[j]; rss[t][j] = ss[j]; }
    __syncthreads();
    for (int off = PPI / 2; off > 0; off >>= 1) {
        if (pg < off) {
            #pragma unroll
            for (int j = 0; j < 8; ++j) {
                rs[t][j]  += rs[t + off * CPT][j];
                rss[t][j] += rss[t + off * CPT][j];
            }
        }
        __syncthreads();
    }
    if (pg == 0) {
        #pragma unroll
        for (int j = 0; j < 8; ++j)
            partial[(size_t)(co * 8 + j) * 256 + blockIdx.x] = make_float2(rs[t][j], rss[t][j]);
    }
}

// ================= BN stats over NCHW f32 (stage 4 raw z): partial[c*B + b] =================
__global__ __launch_bounds__(256) void bn_stats_nchw(const float* __restrict__ raw,
                                                     float2* __restrict__ partial, int C)
{
    int c = blockIdx.x, b = blockIdx.y;
    size_t base = ((size_t)(b * C + c)) * HW;
    const float4* p = (const float4*)(raw + base);
    float s = 0.f, ss = 0.f;
    for (int i = threadIdx.x; i < HW / 4; i += 256) {
        float4 v = p[i];
        s  += v.x + v.y + v.z + v.w;
        ss += v.x * v.x + v.y * v.y + v.z * v.z + v.w * v.w;
    }
    __shared__ float rs[256], rss[256];
    rs[threadIdx.x] = s; rss[threadIdx.x] = ss;
    __syncthreads();
    for (int off = 128; off; off >>= 1) {
        if (threadIdx.x < off) {
            rs[threadIdx.x]  += rs[threadIdx.x + off];
            rss[threadIdx.x] += rss[threadIdx.x + off];
        }
        __syncthreads();
    }
    if (threadIdx.x == 0)
        partial[(size_t)c * gridDim.y + b] = make_float2(rs[0], rss[0]);
}

// ================= finalize: mean/var -> (a, b) =================
__global__ void bn_finalize_kernel(const float2* __restrict__ partial,
                                   const float* __restrict__ gamma,
                                   const float* __restrict__ beta,
                                   float2* __restrict__ coef, int C, int nchunk)
{
    int c = threadIdx.x;
    if (c >= C) return;
    float s = 0.f, ss = 0.f;
    for (int i = 0; i < nchunk; ++i) {
        float2 p = partial[(size_t)c * nchunk + i];
        s += p.x; ss += p.y;
    }
    const float N = 524288.f;
    float m = s / N;
    float v = ss / N - m * m;
    float rsq = rsqrtf(v + 1e-5f);
    float a = gamma[c] * rsq;
    coef[c] = make_float2(a, beta[c] - m * a);
}

// ================= stage-4 in-place NCHW f32 normalize + leaky =================
__global__ __launch_bounds__(256) void bn_apply_nchw(float* __restrict__ data,
                                                     const float2* __restrict__ coef)
{
    size_t q = (size_t)blockIdx.x * 256 + threadIdx.x;
    int c = (int)((q >> 14) & 255);
    float2 ab = coef[c];
    float4* p = (float4*)data;
    float4 v = p[q];
    float x0 = ab.x * v.x + ab.y; v.x = x0 > 0.f ? x0 : 0.01f * x0;
    float x1 = ab.x * v.y + ab.y; v.y = x1 > 0.f ? x1 : 0.01f * x1;
    float x2 = ab.x * v.z + ab.y; v.z = x2 > 0.f ? x2 : 0.01f * x2;
    float x3 = ab.x * v.w + ab.y; v.w = x3 > 0.f ? x3 : 0.01f * x3;
    p[q] = v;
}

// ================= aux outputs =================
__global__ void patches_kernel(const float* __restrict__ x, const int* __restrict__ hw,
                               float* __restrict__ out)
{
    int bs = blockIdx.x;
    int b = bs >> 5;
    int h = hw[bs * 2], w = hw[bs * 2 + 1];
    int t = threadIdx.x;
    if (t < 243) {
        int c = t / 81, r = (t / 9) % 9, cc = t % 9;
        out[(size_t)bs * 243 + t] =
            x[((size_t)(b * 3 + c)) * HW + (size_t)(h - 4 + r) * IMG_W + (w - 4 + cc)];
    }
}

__global__ void gather_kernel(const float* __restrict__ z, const int* __restrict__ hw,
                              float* __restrict__ out)
{
    int bs = blockIdx.x;
    int b = bs >> 5;
    int h = hw[bs * 2], w = hw[bs * 2 + 1];
    int l = threadIdx.x;
    out[(size_t)bs * 256 + l] = z[((size_t)(b * 256 + l)) * HW + (size_t)h * IMG_W + w];
}

__global__ __launch_bounds__(256) void recon_kernel(const float* __restrict__ za,
                                                    const float* __restrict__ rw,
                                                    const float* __restrict__ rb,
                                                    float* __restrict__ out)
{
    int wave = threadIdx.x >> 6, lane = threadIdx.x & 63;
    int n0 = blockIdx.x * 16 + wave * 4;
    float acc[4][8];
    #pragma unroll
    for (int j = 0; j < 4; ++j)
        #pragma unroll
        for (int bb = 0; bb < 8; ++bb) acc[j][bb] = 0.f;

    for (int i = 0; i < 32; ++i) {
        int k = i * 256 + lane * 4;
        float4 wv[4];
        #pragma unroll
        for (int j = 0; j < 4; ++j)
            wv[j] = *(const float4*)&rw[(size_t)(n0 + j) * 8192 + k];
        #pragma unroll
        for (int bb = 0; bb < 8; ++bb) {
            float4 zv = *(const float4*)&za[(size_t)bb * 8192 + k];
            #pragma unroll
            for (int j = 0; j < 4; ++j)
                acc[j][bb] += zv.x * wv[j].x + zv.y * wv[j].y + zv.z * wv[j].z + zv.w * wv[j].w;
        }
    }
    #pragma unroll
    for (int j = 0; j < 4; ++j)
        #pragma unroll
        for (int bb = 0; bb < 8; ++bb) {
            float v = acc[j][bb];
            #pragma unroll
            for (int off = 32; off; off >>= 1) v += __shfl_down(v, off);
            if (lane == 0) out[(size_t)bb * 7776 + n0 + j] = v + rb[n0 + j];
        }
}

extern "C" void kernel_launch(void* const* d_in, const int* in_sizes, int n_in,
                              void* d_out, int out_size, void* d_ws, size_t ws_size,
                              hipStream_t stream) {
    (void)in_sizes; (void)n_in; (void)out_size; (void)ws_size;

    const float* x        = (const float*)d_in[0];
    const int* anchors    = (const int*)d_in[1];
    const int* positives  = (const int*)d_in[2];
    const float* w1 = (const float*)d_in[3];  const float* b1 = (const float*)d_in[4];
    const float* g1 = (const float*)d_in[5];  const float* be1 = (const float*)d_in[6];
    const float* w2 = (const float*)d_in[7];  const float* b2 = (const float*)d_in[8];
    const float* g2 = (const float*)d_in[9];  const float* be2 = (const float*)d_in[10];
    const float* w3 = (const float*)d_in[11]; const float* b3 = (const float*)d_in[12];
    const float* g3 = (const float*)d_in[13]; const float* be3 = (const float*)d_in[14];
    const float* w4 = (const float*)d_in[15]; const float* b4 = (const float*)d_in[16];
    const float* g4 = (const float*)d_in[17]; const float* be4 = (const float*)d_in[18];
    const float* rw = (const float*)d_in[19]; const float* rb = (const float*)d_in[20];

    float* z  = (float*)d_out;                 // [8][256][256][256] f32 (raw4 then normalized)
    float* xa = z + 134217728;
    float* xr = xa + 62208;
    float* za = xr + 62208;
    float* zp = za + 65536;

    // raw1/raw2 (NHWC bf16) overlay the z region (dead before conv4 overwrites z)
    char* zb = (char*)d_out;
    unsigned short* raw1 = (unsigned short*)zb;                 // 33,554,432 B
    unsigned short* raw2 = (unsigned short*)(zb + 33554432ull); // 67,108,864 B

    char* ws = (char*)d_ws;
    unsigned short* wp   = (unsigned short*)ws;                 // <= 589,824 B
    float2* partial = (float2*)(ws + 1048576ull);               // 524,288 B
    float2* coef1   = (float2*)(ws + 1703936ull);               // 4 x 2 KB
    float2* coef2   = coef1 + 256;
    float2* coef3   = coef2 + 256;
    float2* coef4   = coef3 + 256;
    unsigned short* raw3 = (unsigned short*)(ws + 2097152ull);  // 134,217,728 B -> ends ~136.3 MB

    // ---- stage 1: direct conv (f32 NCHW in -> bf16 NHWC raw) ----
    conv1_direct<<<dim3(64, 2, 8), 256, 0, stream>>>(x, w1, b1, raw1);
    bn_stats_nhwc<32><<<256, 256, 0, stream>>>(raw1, partial);
    bn_finalize_kernel<<<1, 256, 0, stream>>>(partial, g1, be1, coef1, 32, 256);

    // ---- stage 2 ----
    repack_w<<<(64 * 288 + 255) / 256, 256, 0, stream>>>(w2, wp, 64, 32);
    conv_mfma<32, 64, false><<<dim3(512, 1, 8), 256, 0, stream>>>(raw1, coef1, wp, b2, raw2);
    bn_stats_nhwc<64><<<256, 256, 0, stream>>>(raw2, partial);
    bn_finalize_kernel<<<1, 256, 0, stream>>>(partial, g2, be2, coef2, 64, 256);

    // ---- stage 3 ----
    repack_w<<<(128 * 576 + 255) / 256, 256, 0, stream>>>(w3, wp, 128, 64);
    conv_mfma<64, 128, false><<<dim3(1024, 1, 8), 256, 0, stream>>>(raw2, coef2, wp, b3, raw3);
    bn_stats_nhwc<128><<<256, 256, 0, stream>>>(raw3, partial);
    bn_finalize_kernel<<<1, 256, 0, stream>>>(partial, g3, be3, coef3, 128, 256);

    // ---- stage 4: MFMA conv -> raw NCHW f32 directly in d_out ----
    repack_w<<<(256 * 1152 + 255) / 256, 256, 0, stream>>>(w4, wp, 256, 128);
    conv_mfma<128, 256, true><<<dim3(2048, 1, 8), 256, 0, stream>>>(raw3, coef3, wp, b4, z);
    bn_stats_nchw<<<dim3(256, 8), 256, 0, stream>>>(z, partial, 256);
    bn_finalize_kernel<<<1, 256, 0, stream>>>(partial, g4, be4, coef4, 256, 8);
    bn_apply_nchw<<<131072, 256, 0, stream>>>(z, coef4);

    // ---- aux outputs ----
    patches_kernel<<<256, 256, 0, stream>>>(x, anchors, xa);
    gather_kernel<<<256, 256, 0, stream>>>(z, anchors, za);
    gather_kernel<<<256, 256, 0, stream>>>(z, positives, zp);
    recon_kernel<<<486, 256, 0, stream>>>(za, rw, rb, xr);
}

// Round 3
// 809.549 us; speedup vs baseline: 9.8665x; 1.7287x over previous
//
#include <hip/hip_runtime.h>
#include <hip/hip_bf16.h>

#define HW 65536
constexpr int IMG_W = 256;

typedef __attribute__((ext_vector_type(8))) short short8;
typedef __attribute__((ext_vector_type(4))) float f32x4;

__device__ __forceinline__ float bf2f(unsigned short u) {
    return __uint_as_float(((unsigned)u) << 16);
}
__device__ __forceinline__ unsigned short f2bf(float f) {
    __hip_bfloat16 h = __float2bfloat16(f);
    return *reinterpret_cast<unsigned short*>(&h);
}

// ================= stage 1: direct 3x3 conv, NCHW f32 in -> NHWC bf16 raw out =================
__global__ __launch_bounds__(256) void conv1_direct(
    const float* __restrict__ x, const float* __restrict__ wt,
    const float* __restrict__ bias, unsigned short* __restrict__ outraw)
{
    constexpr int CIN = 3, COUT = 32, OCB = 16;
    const int tile = blockIdx.x;
    const int ty0 = (tile >> 3) << 5;
    const int tx0 = (tile & 7) << 5;
    const int oc0 = blockIdx.y * OCB;
    const int b = blockIdx.z;

    __shared__ alignas(16) float s_in[CIN][34][36];
    __shared__ alignas(16) float s_w[CIN][9][OCB];

    const int tid = threadIdx.x;
    const int lx = tid & 31;
    const int ly = tid >> 5;

    float acc[4][OCB];
    #pragma unroll
    for (int j = 0; j < 4; ++j)
        #pragma unroll
        for (int oc = 0; oc < OCB; ++oc) acc[j][oc] = 0.f;

    for (int idx = tid; idx < CIN * 34 * 34; idx += 256) {
        int ic  = idx / (34 * 34);
        int rem = idx - ic * (34 * 34);
        int r   = rem / 34;
        int cc  = rem - r * 34;
        int gy = ty0 - 1 + r, gx = tx0 - 1 + cc;
        float v = 0.f;
        if ((unsigned)gy < 256u && (unsigned)gx < 256u)
            v = x[((size_t)(b * CIN + ic)) * HW + (size_t)gy * IMG_W + gx];
        s_in[ic][r][cc] = v;
    }
    for (int idx = tid; idx < CIN * 9 * OCB; idx += 256) {
        int oc  = idx & (OCB - 1);
        int t2  = idx >> 4;
        int tap = t2 % 9;
        int ic  = t2 / 9;
        s_w[ic][tap][oc] = wt[((size_t)(oc0 + oc) * CIN + ic) * 9 + tap];
    }
    __syncthreads();

    for (int ic = 0; ic < CIN; ++ic) {
        #pragma unroll
        for (int tap = 0; tap < 9; ++tap) {
            const int dy = tap / 3, dx = tap % 3;
            float wr[OCB];
            #pragma unroll
            for (int q = 0; q < OCB / 4; ++q)
                *(float4*)&wr[q * 4] = *(const float4*)&s_w[ic][tap][q * 4];
            #pragma unroll
            for (int j = 0; j < 4; ++j) {
                float iv = s_in[ic][ly + 8 * j + dy][lx + dx];
                #pragma unroll
                for (int oc = 0; oc < OCB; ++oc) acc[j][oc] += iv * wr[oc];
            }
        }
    }

    #pragma unroll
    for (int j = 0; j < 4; ++j) {
        const size_t p = ((size_t)b << 16) + (size_t)((ty0 + ly + 8 * j) << 8) + tx0 + lx;
        short8 v0, v1;
        #pragma unroll
        for (int k = 0; k < 8; ++k) {
            v0[k] = (short)f2bf(acc[j][k] + bias[oc0 + k]);
            v1[k] = (short)f2bf(acc[j][8 + k] + bias[oc0 + 8 + k]);
        }
        *(short8*)&outraw[p * COUT + oc0]     = v0;
        *(short8*)&outraw[p * COUT + oc0 + 8] = v1;
    }
}

// ================= weight repack: [oc][ic][3][3] f32 -> [k/8][oc][8] bf16 (k = tap*CIN+ic) ====
__global__ void repack2(const float* __restrict__ w, unsigned short* __restrict__ wp,
                        int COUT, int CIN)
{
    int i = blockIdx.x * 256 + threadIdx.x;
    int K9 = 9 * CIN;
    if (i >= COUT * K9) return;
    int oc = i / K9, k = i - oc * K9;
    int tap = k / CIN, ic = k - tap * CIN;
    wp[(size_t)(k >> 3) * COUT * 8 + oc * 8 + (k & 7)] =
        f2bf(w[((size_t)(oc * CIN + ic)) * 9 + tap]);
}

// ================= MFMA implicit-GEMM 3x3 conv, fused prev-BN staging + fused stats ==========
// wave tile: 64 px (4 rows x 16 cols) x 64 oc. Block: WM x WN waves.
template<int CIN, int COUT, int WM, int WN>
__global__ __launch_bounds__(256, 3) void conv_mfma2(
    const unsigned short* __restrict__ in, const float2* __restrict__ coef,
    const unsigned short* __restrict__ wp, const float* __restrict__ bias,
    unsigned short* __restrict__ outraw, float2* __restrict__ partial)
{
    constexpr int CINP = CIN + 8;
    constexpr int ROWS = WM * 4;
    constexpr int TILES = (256 / ROWS) * 16;
    constexpr int NOC = COUT / (WN * 64);
    constexpr int NCHUNK = TILES * 8;
    constexpr int ICB = CIN / 32;
    constexpr int NOCT = CIN / 8;

    __shared__ alignas(16) short s_in[(ROWS + 2) * 18 * CINP];
    __shared__ float2 s_coef[CIN];
    __shared__ float2 s_stat[4][64];

    const int bx = blockIdx.x;
    const int tile = bx / NOC;
    const int oc0 = (bx - tile * NOC) * (WN * 64);
    const int b = blockIdx.z;
    const int ty0 = (tile >> 4) * ROWS;
    const int tx0 = (tile & 15) * 16;
    const int tid = threadIdx.x;

    if (tid < CIN) s_coef[tid] = coef[tid];
    __syncthreads();

    const size_t bbase = (size_t)b << 16;
    for (int idx = tid; idx < (ROWS + 2) * 18 * NOCT; idx += 256) {
        int ic8 = idx % NOCT;
        int rc  = idx / NOCT;
        int c = rc % 18, r = rc / 18;
        int gy = ty0 - 1 + r, gx = tx0 - 1 + c;
        short8 v = (short8)0;
        if ((unsigned)gy < 256u && (unsigned)gx < 256u) {
            short8 rawv = *(const short8*)&in[(bbase + (size_t)(gy << 8) + gx) * CIN + ic8 * 8];
            #pragma unroll
            for (int j = 0; j < 8; ++j) {
                float2 ab = s_coef[ic8 * 8 + j];
                float xv = ab.x * bf2f((unsigned short)rawv[j]) + ab.y;
                xv = xv > 0.f ? xv : 0.01f * xv;
                v[j] = (short)f2bf(xv);
            }
        }
        *(short8*)&s_in[(r * 18 + c) * CINP + ic8 * 8] = v;
    }
    __syncthreads();

    const int lane = tid & 63;
    const int wv = tid >> 6;
    const int wm = wv / WN, wn = wv % WN;
    const int ln = lane & 15;
    const int grp = lane >> 4;

    f32x4 acc[4][4] = {};

    // B base: lane reads oc row (oc0 + wn*64 + g*16 + ln), k-chunk (kc0 + icb*4 + grp)
    const unsigned short* wpb = wp + ((size_t)grp * COUT + oc0 + wn * 64 + ln) * 8;

    for (int tap = 0; tap < 9; ++tap) {
        const int dy = tap / 3, dx = tap - dy * 3;
        const int arow = (wm * 4 + dy) * 18 + ln + dx;
        const int kc0 = tap * (CIN / 8);
        #pragma unroll
        for (int icb = 0; icb < ICB; ++icb) {
            short8 bfr[4];
            #pragma unroll
            for (int g = 0; g < 4; ++g)
                bfr[g] = *(const short8*)&wpb[((size_t)(kc0 + icb * 4) * COUT + g * 16) * 8];
            #pragma unroll
            for (int f = 0; f < 4; ++f) {
                short8 av = *(const short8*)&s_in[(arow + f * 18) * CINP + icb * 32 + grp * 8];
                #pragma unroll
                for (int g = 0; g < 4; ++g)
                    acc[f][g] = __builtin_amdgcn_mfma_f32_16x16x32_bf16(av, bfr[g], acc[f][g], 0, 0, 0);
            }
        }
    }

    // ---- epilogue: NHWC bf16 raw store + per-block channel stats ----
    #pragma unroll
    for (int g = 0; g < 4; ++g) {
        const int oc = oc0 + wn * 64 + g * 16 + ln;
        const float bv = bias[oc];
        float s = 0.f, q = 0.f;
        #pragma unroll
        for (int f = 0; f < 4; ++f) {
            const int rr = ty0 + wm * 4 + f;
            const size_t rowbase = (bbase + (size_t)(rr << 8) + tx0 + grp * 4) * COUT + oc;
            #pragma unroll
            for (int reg = 0; reg < 4; ++reg) {
                float v = acc[f][g][reg] + bv;
                outraw[rowbase + (size_t)reg * COUT] = f2bf(v);
                s += v; q += v * v;
            }
        }
        s += __shfl_down(s, 32); q += __shfl_down(q, 32);
        s += __shfl_down(s, 16); q += __shfl_down(q, 16);
        if (grp == 0) s_stat[wv][g * 16 + ln] = make_float2(s, q);
    }
    __syncthreads();
    if (tid < WN * 64) {
        const int wn2 = tid >> 6;
        const int ol = tid & 63;
        float sx = 0.f, sq = 0.f;
        #pragma unroll
        for (int m = 0; m < WM; ++m) {
            float2 p = s_stat[m * WN + wn2][ol];
            sx += p.x; sq += p.y;
        }
        const int chunk = b * TILES + tile;
        partial[(size_t)(oc0 + wn2 * 64 + ol) * NCHUNK + chunk] = make_float2(sx, sq);
    }
}

// ================= stage-1 BN stats over NHWC bf16 raw =================
template<int C>
__global__ __launch_bounds__(256) void bn_stats_nhwc(const unsigned short* __restrict__ raw,
                                                     float2* __restrict__ partial)
{
    constexpr int CPT = C / 8;
    constexpr int PPI = 256 / CPT;
    const int t = threadIdx.x;
    const int co = t % CPT, pg = t / CPT;
    const int p0 = blockIdx.x * 2048;
    float s[8], ss[8];
    #pragma unroll
    for (int j = 0; j < 8; ++j) { s[j] = 0.f; ss[j] = 0.f; }
    for (int p = p0 + pg; p < p0 + 2048; p += PPI) {
        short8 v = *(const short8*)&raw[(size_t)p * C + co * 8];
        #pragma unroll
        for (int j = 0; j < 8; ++j) {
            float xv = bf2f((unsigned short)v[j]);
            s[j] += xv; ss[j] += xv * xv;
        }
    }
    __shared__ float rs[256][8], rss[256][8];
    #pragma unroll
    for (int j = 0; j < 8; ++j) { rs[t][j] = s[j]; rss[t][j] = ss[j]; }
    __syncthreads();
    for (int off = PPI / 2; off > 0; off >>= 1) {
        if (pg < off) {
            #pragma unroll
            for (int j = 0; j < 8; ++j) {
                rs[t][j]  += rs[t + off * CPT][j];
                rss[t][j] += rss[t + off * CPT][j];
            }
        }
        __syncthreads();
    }
    if (pg == 0) {
        #pragma unroll
        for (int j = 0; j < 8; ++j)
            partial[(size_t)(co * 8 + j) * 256 + blockIdx.x] = make_float2(rs[t][j], rss[t][j]);
    }
}

// ================= finalize (stage 1 layout: [c][256]) =================
__global__ void bn_finalize_kernel(const float2* __restrict__ partial,
                                   const float* __restrict__ gamma,
                                   const float* __restrict__ beta,
                                   float2* __restrict__ coef, int C, int nchunk)
{
    int c = threadIdx.x;
    if (c >= C) return;
    float s = 0.f, ss = 0.f;
    for (int i = 0; i < nchunk; ++i) {
        float2 p = partial[(size_t)c * nchunk + i];
        s += p.x; ss += p.y;
    }
    const float N = 524288.f;
    float m = s / N;
    float v = ss / N - m * m;
    float rsq = rsqrtf(v + 1e-5f);
    float a = gamma[c] * rsq;
    coef[c] = make_float2(a, beta[c] - m * a);
}

// ================= finalize v2: one block per channel, [c][NCHUNK] =================
template<int NCHUNK>
__global__ __launch_bounds__(256) void bn_finalize2(const float2* __restrict__ partial,
                                                    const float* __restrict__ gamma,
                                                    const float* __restrict__ beta,
                                                    float2* __restrict__ coef)
{
    const int c = blockIdx.x, t = threadIdx.x;
    float s = 0.f, q = 0.f;
    for (int i = t; i < NCHUNK; i += 256) {
        float2 p = partial[(size_t)c * NCHUNK + i];
        s += p.x; q += p.y;
    }
    __shared__ float rs[256], rq[256];
    rs[t] = s; rq[t] = q;
    __syncthreads();
    for (int off = 128; off; off >>= 1) {
        if (t < off) { rs[t] += rs[t + off]; rq[t] += rq[t + off]; }
        __syncthreads();
    }
    if (t == 0) {
        const float N = 524288.f;
        float m = rs[0] / N;
        float v = rq[0] / N - m * m;
        float a = gamma[c] * rsqrtf(v + 1e-5f);
        coef[c] = make_float2(a, beta[c] - m * a);
    }
}

// ================= stage-4 apply: raw NHWC bf16 -> normalized NCHW f32 z =================
// block: 32 px x 256 oc tile; LDS transpose with XOR swizzle (<=4-way conflicts).
__global__ __launch_bounds__(256) void apply_t(const unsigned short* __restrict__ raw,
                                               const float2* __restrict__ coef,
                                               float* __restrict__ z)
{
    __shared__ float s_t[256 * 36];
    __shared__ float2 s_c[256];
    const int t = threadIdx.x;
    s_c[t] = coef[t];
    __syncthreads();

    const size_t p0 = (size_t)blockIdx.x * 32;
    const int o = t & 31, prow = t >> 5;
    #pragma unroll
    for (int it = 0; it < 4; ++it) {
        const int pxi = prow + it * 8;
        short8 v = *(const short8*)&raw[(p0 + pxi) * 256 + o * 8];
        #pragma unroll
        for (int j = 0; j < 8; ++j) {
            const int oc = o * 8 + j;
            float2 ab = s_c[oc];
            float xv = ab.x * bf2f((unsigned short)v[j]) + ab.y;
            xv = xv > 0.f ? xv : 0.01f * xv;
            s_t[oc * 36 + (pxi ^ ((o & 7) * 4))] = xv;
        }
    }
    __syncthreads();

    const int Q = t & 7, ocr = t >> 3;
    const int b = (int)(p0 >> 16);
    const int pxl = (int)(p0 & 65535);
    #pragma unroll
    for (int pass = 0; pass < 8; ++pass) {
        const int oc = ocr + pass * 32;
        const int w = (oc >> 3) & 7;
        f32x4 vv = *(const f32x4*)&s_t[oc * 36 + ((Q ^ w) * 4)];
        *(f32x4*)&z[(((size_t)(b * 256 + oc)) << 16) + pxl + Q * 4] = vv;
    }
}

// ================= aux outputs =================
__global__ void patches_kernel(const float* __restrict__ x, const int* __restrict__ hw,
                               float* __restrict__ out)
{
    int bs = blockIdx.x;
    int b = bs >> 5;
    int h = hw[bs * 2], w = hw[bs * 2 + 1];
    int t = threadIdx.x;
    if (t < 243) {
        int c = t / 81, r = (t / 9) % 9, cc = t % 9;
        out[(size_t)bs * 243 + t] =
            x[((size_t)(b * 3 + c)) * HW + (size_t)(h - 4 + r) * IMG_W + (w - 4 + cc)];
    }
}

__global__ void gather_kernel(const float* __restrict__ z, const int* __restrict__ hw,
                              float* __restrict__ out)
{
    int bs = blockIdx.x;
    int b = bs >> 5;
    int h = hw[bs * 2], w = hw[bs * 2 + 1];
    int l = threadIdx.x;
    out[(size_t)bs * 256 + l] = z[((size_t)(b * 256 + l)) * HW + (size_t)h * IMG_W + w];
}

__global__ __launch_bounds__(256) void recon_kernel(const float* __restrict__ za,
                                                    const float* __restrict__ rw,
                                                    const float* __restrict__ rb,
                                                    float* __restrict__ out)
{
    int wave = threadIdx.x >> 6, lane = threadIdx.x & 63;
    int n0 = blockIdx.x * 16 + wave * 4;
    float acc[4][8];
    #pragma unroll
    for (int j = 0; j < 4; ++j)
        #pragma unroll
        for (int bb = 0; bb < 8; ++bb) acc[j][bb] = 0.f;

    for (int i = 0; i < 32; ++i) {
        int k = i * 256 + lane * 4;
        float4 wv[4];
        #pragma unroll
        for (int j = 0; j < 4; ++j)
            wv[j] = *(const float4*)&rw[(size_t)(n0 + j) * 8192 + k];
        #pragma unroll
        for (int bb = 0; bb < 8; ++bb) {
            float4 zv = *(const float4*)&za[(size_t)bb * 8192 + k];
            #pragma unroll
            for (int j = 0; j < 4; ++j)
                acc[j][bb] += zv.x * wv[j].x + zv.y * wv[j].y + zv.z * wv[j].z + zv.w * wv[j].w;
        }
    }
    #pragma unroll
    for (int j = 0; j < 4; ++j)
        #pragma unroll
        for (int bb = 0; bb < 8; ++bb) {
            float v = acc[j][bb];
            #pragma unroll
            for (int off = 32; off; off >>= 1) v += __shfl_down(v, off);
            if (lane == 0) out[(size_t)bb * 7776 + n0 + j] = v + rb[n0 + j];
        }
}

extern "C" void kernel_launch(void* const* d_in, const int* in_sizes, int n_in,
                              void* d_out, int out_size, void* d_ws, size_t ws_size,
                              hipStream_t stream) {
    (void)in_sizes; (void)n_in; (void)out_size; (void)ws_size;

    const float* x        = (const float*)d_in[0];
    const int* anchors    = (const int*)d_in[1];
    const int* positives  = (const int*)d_in[2];
    const float* w1 = (const float*)d_in[3];  const float* b1 = (const float*)d_in[4];
    const float* g1 = (const float*)d_in[5];  const float* be1 = (const float*)d_in[6];
    const float* w2 = (const float*)d_in[7];  const float* b2 = (const float*)d_in[8];
    const float* g2 = (const float*)d_in[9];  const float* be2 = (const float*)d_in[10];
    const float* w3 = (const float*)d_in[11]; const float* b3 = (const float*)d_in[12];
    const float* g3 = (const float*)d_in[13]; const float* be3 = (const float*)d_in[14];
    const float* w4 = (const float*)d_in[15]; const float* b4 = (const float*)d_in[16];
    const float* g4 = (const float*)d_in[17]; const float* be4 = (const float*)d_in[18];
    const float* rw = (const float*)d_in[19]; const float* rb = (const float*)d_in[20];

    float* z  = (float*)d_out;                 // [8][256][256][256] f32 normalized (final)
    float* xa = z + 134217728;
    float* xr = xa + 62208;
    float* za = xr + 62208;
    float* zp = za + 65536;

    // raw1/raw2/raw3 (NHWC bf16) overlay the z region (dead before apply_t writes z)
    char* zb = (char*)d_out;
    unsigned short* raw1 = (unsigned short*)zb;                  //  33,554,432 B
    unsigned short* raw2 = (unsigned short*)(zb + 33554432ull);  //  67,108,864 B
    unsigned short* raw3 = (unsigned short*)(zb + 100663296ull); // 134,217,728 B (ends 234.9 MB)

    char* ws = (char*)d_ws;
    unsigned short* wp   = (unsigned short*)ws;                  // <= 589,824 B
    float2* partial = (float2*)(ws + 1048576ull);                // <= 8,388,608 B
    float2* coef1   = (float2*)(ws + 10485760ull);
    float2* coef2   = coef1 + 256;
    float2* coef3   = coef2 + 256;
    float2* coef4   = coef3 + 256;
    unsigned short* raw4 = (unsigned short*)(ws + 16777216ull);  // 134,217,728 B (ends 151 MB)

    // ---- stage 1 ----
    conv1_direct<<<dim3(64, 2, 8), 256, 0, stream>>>(x, w1, b1, raw1);
    bn_stats_nhwc<32><<<256, 256, 0, stream>>>(raw1, partial);
    bn_finalize_kernel<<<1, 256, 0, stream>>>(partial, g1, be1, coef1, 32, 256);

    // ---- stage 2: 256px x 64oc blocks ----
    repack2<<<(64 * 288 + 255) / 256, 256, 0, stream>>>(w2, wp, 64, 32);
    conv_mfma2<32, 64, 4, 1><<<dim3(256, 1, 8), 256, 0, stream>>>(raw1, coef1, wp, b2, raw2, partial);
    bn_finalize2<2048><<<64, 256, 0, stream>>>(partial, g2, be2, coef2);

    // ---- stage 3: 128px x 128oc blocks ----
    repack2<<<(128 * 576 + 255) / 256, 256, 0, stream>>>(w3, wp, 128, 64);
    conv_mfma2<64, 128, 2, 2><<<dim3(512, 1, 8), 256, 0, stream>>>(raw2, coef2, wp, b3, raw3, partial);
    bn_finalize2<4096><<<128, 256, 0, stream>>>(partial, g3, be3, coef3);

    // ---- stage 4: 128px x 128oc blocks, raw bf16 NHWC to ws ----
    repack2<<<(256 * 1152 + 255) / 256, 256, 0, stream>>>(w4, wp, 256, 128);
    conv_mfma2<128, 256, 2, 2><<<dim3(1024, 1, 8), 256, 0, stream>>>(raw3, coef3, wp, b4, raw4, partial);
    bn_finalize2<4096><<<256, 256, 0, stream>>>(partial, g4, be4, coef4);

    // ---- stage-4 apply + NHWC->NCHW transpose into z ----
    apply_t<<<16384, 256, 0, stream>>>(raw4, coef4, z);

    // ---- aux outputs ----
    patches_kernel<<<256, 256, 0, stream>>>(x, anchors, xa);
    gather_kernel<<<256, 256, 0, stream>>>(z, anchors, za);
    gather_kernel<<<256, 256, 0, stream>>>(z, positives, zp);
    recon_kernel<<<486, 256, 0, stream>>>(za, rw, rb, xr);
}